// Round 5
// baseline (388.884 us; speedup 1.0000x reference)
//
#include <hip/hip_runtime.h>
#include <hip/hip_bf16.h>

// SegmentConv2d: fake-quant-int8 (global for x, per-128-oc-chunk for w) + 3x3 pad1 conv + bias.
// int8 path: quantize to real int8, conv with mfma_i32_16x16x64_i8 (exact int accum),
// scale+bias epilogue.
//
// Shapes: x[8][256][128][128] f32, w[512][256][3][3] f32, bias[512], out[8][512][128][128] f32.
//
// ws layout:
//   [0..63]           : amax[5] (uint bits, written by k_amax2 - no atomics)
//   [64..79]          : 16B zeros (OOB redirect for global_load_lds)
//   [256..13567]      : per-block amax partials float[3328] (x: 0..2047, w: 2048..3199)
//   [16384..)         : qx int8 NHWC  [n][h][w][c]  = 33,554,432 B
//   [16384+32M..)     : qw int8       [r*3+s][oc][c] = 1,179,648 B

typedef int i32x4 __attribute__((ext_vector_type(4)));

__device__ __forceinline__ void llds16(const void* g, void* l) {
    __builtin_amdgcn_global_load_lds(
        (const __attribute__((address_space(1))) void*)g,
        (__attribute__((address_space(3))) void*)l,
        16, 0, 0);
}

__device__ __forceinline__ float f4max(float4 v) {
    return fmaxf(fmaxf(fabsf(v.x), fabsf(v.y)), fmaxf(fabsf(v.z), fabsf(v.w)));
}

// ---------------- amax stage 1: per-block partial maxima (NO atomics) ----------------
// Blocks [0,2048): x, 16 independent float4 loads in flight. Blocks [2048,3200): w,
// 288 blocks per 128-oc chunk. partial[blockIdx.x] = block max|.|.
// Round-4 had one atomicMax per wave to a single address (8k+ same-line atomics
// serialize at the coherence point) -- replaced by partials + k_amax2.
__global__ __launch_bounds__(256) void k_amax(const float4* __restrict__ x,
                                              const float4* __restrict__ w4,
                                              float* __restrict__ part) {
    __shared__ float red[4];
    int t = threadIdx.x;
    float m = 0.f;
    if (blockIdx.x < 2048) {
        int tid = blockIdx.x * 256 + t;
        float4 v[16];
#pragma unroll
        for (int k = 0; k < 16; ++k)
            v[k] = x[(size_t)tid + (size_t)k * 524288];
#pragma unroll
        for (int k = 0; k < 16; ++k) m = fmaxf(m, f4max(v[k]));
    } else {
        int b = blockIdx.x - 2048;          // 0..1151
        int chunk = b / 288;
        int tid = (b - chunk * 288) * 256 + t;
        m = f4max(w4[(size_t)chunk * 73728 + tid]);
    }
    for (int off = 32; off > 0; off >>= 1) m = fmaxf(m, __shfl_xor(m, off, 64));
    if ((t & 63) == 0) red[t >> 6] = m;
    __syncthreads();
    if (t == 0)
        part[blockIdx.x] = fmaxf(fmaxf(red[0], red[1]), fmaxf(red[2], red[3]));
}

// ---------------- amax stage 2: reduce partials -> amaxb[0..4] ----------------
__global__ __launch_bounds__(256) void k_amax2(const float* __restrict__ part,
                                               unsigned* __restrict__ amaxb) {
    __shared__ float red[4];
    int t = threadIdx.x;
    float m = 0.f;
#pragma unroll
    for (int k = 0; k < 8; ++k) m = fmaxf(m, part[t + k * 256]);
    for (int off = 32; off > 0; off >>= 1) m = fmaxf(m, __shfl_xor(m, off, 64));
    if ((t & 63) == 0) red[t >> 6] = m;
    __syncthreads();
    if (t == 0)
        amaxb[0] = __float_as_uint(fmaxf(fmaxf(red[0], red[1]), fmaxf(red[2], red[3])));
    // w: one wave per chunk, 288 partials each
    int c = t >> 6, l = t & 63;
    float wm = 0.f;
#pragma unroll
    for (int k = 0; k < 5; ++k) {
        int i = l + k * 64;
        if (i < 288) wm = fmaxf(wm, part[2048 + c * 288 + i]);
    }
    for (int off = 32; off > 0; off >>= 1) wm = fmaxf(wm, __shfl_xor(wm, off, 64));
    if (l == 0) amaxb[1 + c] = __float_as_uint(wm);
}

// ---------------- quantize x : NCHW f32 -> NHWC int8 ----------------
// block = one (n,h) row, 256 threads, NO LDS: each thread loads 16 float4 (16
// c-planes x 4 w, all independent -> 16 loads in flight), register-transposes,
// stores 4x uint4 (16 contiguous c bytes each). Scattered 16B stores merge in L2.
__global__ __launch_bounds__(256) void k_quant_x(const float* __restrict__ x,
                                                 signed char* __restrict__ qx,
                                                 const unsigned* __restrict__ amaxb) {
    float inv = 127.0f / fmaxf(__uint_as_float(amaxb[0]), 1e-12f);
    int row = blockIdx.x;                 // n*128 + h
    int n = row >> 7, h = row & 127;
    int t = threadIdx.x;
    int w4 = t & 31, cg = t >> 5;         // w4: float4 slot along w; cg in [0,8)
    const float* base = x + (size_t)n * 256 * 16384 + (size_t)h * 128 + w4 * 4;
#pragma unroll
    for (int pp = 0; pp < 2; ++pp) {
        int c0 = pp * 128 + cg * 16;
        float4 v[16];
#pragma unroll
        for (int j = 0; j < 16; ++j)
            v[j] = *(const float4*)(base + (size_t)(c0 + j) * 16384);
#pragma unroll
        for (int i = 0; i < 4; ++i) {
            unsigned wds[4];
#pragma unroll
            for (int jg = 0; jg < 4; ++jg) {
                unsigned u = 0;
#pragma unroll
                for (int jj = 0; jj < 4; ++jj) {
                    float f = (&v[jg * 4 + jj].x)[i];
                    int q = (int)fminf(fmaxf(rintf(f * inv), -128.f), 127.f);
                    u |= ((unsigned)(q & 255)) << (8 * jj);
                }
                wds[jg] = u;
            }
            *(uint4*)&qx[(size_t)row * 32768 + (size_t)(w4 * 4 + i) * 256 + c0] =
                make_uint4(wds[0], wds[1], wds[2], wds[3]);
        }
    }
}

// ---------------- quantize w : OIHW f32 -> [rs][oc][c] int8 ----------------
__global__ void k_quant_w(const float* __restrict__ wsrc, signed char* __restrict__ qw,
                          const unsigned* __restrict__ amaxb) {
    int idx = blockIdx.x * 256 + threadIdx.x;   // 131072 = 512 blocks
    int oc = idx >> 8, c = idx & 255;
    float inv = 127.0f / fmaxf(__uint_as_float(amaxb[1 + (oc >> 7)]), 1e-12f);
    const float* src = wsrc + (size_t)idx * 9;
    float v[9];
#pragma unroll
    for (int rs = 0; rs < 9; ++rs) v[rs] = src[rs];
#pragma unroll
    for (int rs = 0; rs < 9; ++rs) {
        float qf = fminf(fmaxf(rintf(v[rs] * inv), -128.f), 127.f);
        qw[((size_t)(rs * 512 + oc)) * 256 + c] = (signed char)(int)qf;
    }
}

// ---------------- conv : implicit GEMM with mfma_i32_16x16x64_i8 ----------------
// grid 4096 (bijective XCD swizzle: each XCD owns one image n), block 256 (4 waves).
// Block tile: 64 oc x 256 px (2 output rows). Wave (rowsel=wid>>1, whalf=wid&1) owns
// 64oc x 64px. 4 phases over cb (64 c each).
//
// Round-5 structure: A (weight) fragments are GATHERED FROM GLOBAL per MFMA (qw is
// L2-resident, 1.2 MB; a wave A-load touches exactly 16 distinct 64B lines = minimum).
// This halves LDS fragment-read cycles (round-4 analysis: ds_read_b128 was the
// co-critical pipe at ~92us floor) and removes wt staging entirely. LDS holds only
// xs, DOUBLE-BUFFERED at 66.5 KB -> still 2 blocks/CU, so next-phase xs prefetch
// hides under the MFMA cluster AND inter-block overlap covers the barrier drain.
// Fragment LDS reads XOR-swizzled (8-way -> 2-way) via permuted GLOBAL source q4.
__global__ __launch_bounds__(256) void k_conv(
    const signed char* __restrict__ qx, const signed char* __restrict__ qw,
    const signed char* __restrict__ zb, const unsigned* __restrict__ amaxb,
    const float* __restrict__ bias, float* __restrict__ out) {
    __shared__ __align__(16) signed char xs[2][4 * 8320];    // 2 x 33280 B
    int orig = blockIdx.x;                      // 0..4095, nwg % 8 == 0
    int wgid = (orig & 7) * 512 + (orig >> 3);  // bijective XCD swizzle
    int rowpair = wgid >> 3, ocg = wgid & 7;
    int n = rowpair >> 6;                       // 64 rowpairs per image
    int h0 = (rowpair & 63) * 2;
    int t = threadIdx.x, wid = t >> 6, lane = t & 63;
    int p = lane & 15, hi = lane >> 4;
    int rowsel = wid >> 1, whalf = wid & 1;

    i32x4 acc[4][4] = {};

    // per-lane base for A gathers: qw[(rs*512 + ocg*64 + mf*16 + p)*256 + cb*64 + hi*16]
    const signed char* wbase = qw + (size_t)(ocg * 64 + p) * 256 + hi * 16;

    auto stageX = [&](int cb, int buf) {
        // xs: 4 rows x 130 w x 4 q4 = 2080 x 16B, lane-linear LDS dest
#pragma unroll
        for (int i = 0; i < 9; ++i) {
            int idx = t + i * 256;
            if (idx < 2080) {
                int rowk = idx / 520;
                int j = idx - rowk * 520;
                int wr = j >> 2, q4 = j & 3;
                int wg = wr - 1;
                int hh = h0 - 1 + rowk;
                int q4s = q4 ^ ((wr >> 1) & 3);
                const signed char* src = (hh >= 0 && hh < 128 && wg >= 0 && wg < 128)
                    ? qx + (size_t)(n * 128 + hh) * 32768 + wg * 256 + cb * 64 + q4s * 16
                    : zb;
                llds16(src, &xs[buf][0] + (size_t)(i * 256 + wid * 64) * 16);
            }
        }
    };

    stageX(0, 0);
    __syncthreads();
#pragma unroll
    for (int cb = 0; cb < 4; ++cb) {
        if (cb < 3) stageX(cb + 1, (cb + 1) & 1);   // prefetch into other buffer
        const signed char* wcb = wbase + cb * 64;
#pragma unroll
        for (int r = 0; r < 3; ++r) {
            int rowk = r + rowsel;
#pragma unroll
            for (int s = 0; s < 3; ++s) {
                i32x4 a[4], b[4];
#pragma unroll
                for (int mf = 0; mf < 4; ++mf)
                    a[mf] = *(const i32x4*)(wcb + (size_t)((r * 3 + s) * 512 + mf * 16) * 256);
#pragma unroll
                for (int nf = 0; nf < 4; ++nf) {
                    int wrow = whalf * 64 + nf * 16 + p + s;
                    b[nf] = *(const i32x4*)&xs[cb & 1][rowk * 8320 + wrow * 64
                                               + ((hi ^ ((wrow >> 1) & 3)) << 4)];
                }
#pragma unroll
                for (int mf = 0; mf < 4; ++mf)
#pragma unroll
                    for (int nf = 0; nf < 4; ++nf)
                        acc[mf][nf] = __builtin_amdgcn_mfma_i32_16x16x64_i8(
                            a[mf], b[nf], acc[mf][nf], 0, 0, 0);
            }
        }
        __syncthreads();                           // xs reads done + prefetch landed
    }

    float sx = fmaxf(__uint_as_float(amaxb[0]), 1e-12f) / 127.0f;
    float sw = fmaxf(__uint_as_float(amaxb[1 + (ocg >> 1)]), 1e-12f) / 127.0f;
    float sc = sx * sw;
    int h = h0 + rowsel;
#pragma unroll
    for (int mf = 0; mf < 4; ++mf)
#pragma unroll
        for (int nf = 0; nf < 4; ++nf)
#pragma unroll
            for (int j = 0; j < 4; ++j) {
                int oc = ocg * 64 + mf * 16 + hi * 4 + j;
                int px = whalf * 64 + nf * 16 + p;
                out[((size_t)(n * 512 + oc) * 128 + h) * 128 + px] =
                    (float)acc[mf][nf][j] * sc + bias[oc];
            }
}

extern "C" void kernel_launch(void* const* d_in, const int* in_sizes, int n_in,
                              void* d_out, int out_size, void* d_ws, size_t ws_size,
                              hipStream_t stream) {
    const float* x    = (const float*)d_in[0];
    const float* wgt  = (const float*)d_in[1];
    const float* bias = (const float*)d_in[2];
    float* out = (float*)d_out;

    unsigned* amaxb = (unsigned*)d_ws;
    float* part = (float*)((char*)d_ws + 256);
    signed char* qx = (signed char*)d_ws + 16384;
    signed char* qw = (signed char*)d_ws + 16384 + 33554432;
    const signed char* zb = (const signed char*)d_ws + 64;   // 16B zeros for OOB redirect

    hipMemsetAsync(d_ws, 0, 256, stream);   // zb zeros (amax slots overwritten by k_amax2)

    k_amax<<<3200, 256, 0, stream>>>((const float4*)x, (const float4*)wgt, part);
    k_amax2<<<1, 256, 0, stream>>>(part, amaxb);
    k_quant_x<<<1024, 256, 0, stream>>>(x, qx, amaxb);
    k_quant_w<<<512, 256, 0, stream>>>(wgt, qw, amaxb);
    k_conv<<<dim3(4096), 256, 0, stream>>>(qx, qw, zb, amaxb, bias, out);
}

// Round 6
// 224.176 us; speedup vs baseline: 1.7347x; 1.7347x over previous
//
#include <hip/hip_runtime.h>
#include <hip/hip_bf16.h>

// SegmentConv2d: fake-quant-int8 (global for x, per-128-oc-chunk for w) + 3x3 pad1 conv + bias.
// int8 path: quantize to real int8, conv with mfma_i32_16x16x64_i8 (exact int accum),
// scale+bias epilogue.
//
// Shapes: x[8][256][128][128] f32, w[512][256][3][3] f32, bias[512], out[8][512][128][128] f32.
//
// ws layout:
//   [0..63]           : amax[5] (uint bits, written by k_amax2 - no atomics)
//   [64..79]          : 16B zeros (OOB redirect for global_load_lds)
//   [256..13567]      : per-block amax partials float[3328] (x: 0..2047, w: 2048..3199)
//   [16384..)         : qx int8 NHWC  [n][h][w][c]  = 33,554,432 B
//   [16384+32M..)     : qw int8       [r*3+s][oc][c] = 1,179,648 B

typedef int i32x4 __attribute__((ext_vector_type(4)));

__device__ __forceinline__ void llds16(const void* g, void* l) {
    __builtin_amdgcn_global_load_lds(
        (const __attribute__((address_space(1))) void*)g,
        (__attribute__((address_space(3))) void*)l,
        16, 0, 0);
}

__device__ __forceinline__ float f4max(float4 v) {
    return fmaxf(fmaxf(fabsf(v.x), fabsf(v.y)), fmaxf(fabsf(v.z), fabsf(v.w)));
}

// ---------------- amax stage 1: per-block partial maxima (NO atomics) ----------------
__global__ __launch_bounds__(256) void k_amax(const float4* __restrict__ x,
                                              const float4* __restrict__ w4,
                                              float* __restrict__ part) {
    __shared__ float red[4];
    int t = threadIdx.x;
    float m = 0.f;
    if (blockIdx.x < 2048) {
        int tid = blockIdx.x * 256 + t;
        float4 v[16];
#pragma unroll
        for (int k = 0; k < 16; ++k)
            v[k] = x[(size_t)tid + (size_t)k * 524288];
#pragma unroll
        for (int k = 0; k < 16; ++k) m = fmaxf(m, f4max(v[k]));
    } else {
        int b = blockIdx.x - 2048;          // 0..1151
        int chunk = b / 288;
        int tid = (b - chunk * 288) * 256 + t;
        m = f4max(w4[(size_t)chunk * 73728 + tid]);
    }
    for (int off = 32; off > 0; off >>= 1) m = fmaxf(m, __shfl_xor(m, off, 64));
    if ((t & 63) == 0) red[t >> 6] = m;
    __syncthreads();
    if (t == 0)
        part[blockIdx.x] = fmaxf(fmaxf(red[0], red[1]), fmaxf(red[2], red[3]));
}

// ---------------- amax stage 2: reduce partials -> amaxb[0..4] ----------------
__global__ __launch_bounds__(256) void k_amax2(const float* __restrict__ part,
                                               unsigned* __restrict__ amaxb) {
    __shared__ float red[4];
    int t = threadIdx.x;
    float m = 0.f;
#pragma unroll
    for (int k = 0; k < 8; ++k) m = fmaxf(m, part[t + k * 256]);
    for (int off = 32; off > 0; off >>= 1) m = fmaxf(m, __shfl_xor(m, off, 64));
    if ((t & 63) == 0) red[t >> 6] = m;
    __syncthreads();
    if (t == 0)
        amaxb[0] = __float_as_uint(fmaxf(fmaxf(red[0], red[1]), fmaxf(red[2], red[3])));
    // w: one wave per chunk, 288 partials each
    int c = t >> 6, l = t & 63;
    float wm = 0.f;
#pragma unroll
    for (int k = 0; k < 5; ++k) {
        int i = l + k * 64;
        if (i < 288) wm = fmaxf(wm, part[2048 + c * 288 + i]);
    }
    for (int off = 32; off > 0; off >>= 1) wm = fmaxf(wm, __shfl_xor(wm, off, 64));
    if (l == 0) amaxb[1 + c] = __float_as_uint(wm);
}

// ---------------- quantize x : NCHW f32 -> NHWC int8 ----------------
// block = one (n,h) row, 256 threads, NO LDS: 16 independent float4 loads in flight,
// register transpose, uint4 stores (merge in L2).
__global__ __launch_bounds__(256) void k_quant_x(const float* __restrict__ x,
                                                 signed char* __restrict__ qx,
                                                 const unsigned* __restrict__ amaxb) {
    float inv = 127.0f / fmaxf(__uint_as_float(amaxb[0]), 1e-12f);
    int row = blockIdx.x;                 // n*128 + h
    int n = row >> 7, h = row & 127;
    int t = threadIdx.x;
    int w4 = t & 31, cg = t >> 5;         // w4: float4 slot along w; cg in [0,8)
    const float* base = x + (size_t)n * 256 * 16384 + (size_t)h * 128 + w4 * 4;
#pragma unroll
    for (int pp = 0; pp < 2; ++pp) {
        int c0 = pp * 128 + cg * 16;
        float4 v[16];
#pragma unroll
        for (int j = 0; j < 16; ++j)
            v[j] = *(const float4*)(base + (size_t)(c0 + j) * 16384);
#pragma unroll
        for (int i = 0; i < 4; ++i) {
            unsigned wds[4];
#pragma unroll
            for (int jg = 0; jg < 4; ++jg) {
                unsigned u = 0;
#pragma unroll
                for (int jj = 0; jj < 4; ++jj) {
                    float f = (&v[jg * 4 + jj].x)[i];
                    int q = (int)fminf(fmaxf(rintf(f * inv), -128.f), 127.f);
                    u |= ((unsigned)(q & 255)) << (8 * jj);
                }
                wds[jg] = u;
            }
            *(uint4*)&qx[(size_t)row * 32768 + (size_t)(w4 * 4 + i) * 256 + c0] =
                make_uint4(wds[0], wds[1], wds[2], wds[3]);
        }
    }
}

// ---------------- quantize w : OIHW f32 -> [rs][oc][c] int8 ----------------
__global__ void k_quant_w(const float* __restrict__ wsrc, signed char* __restrict__ qw,
                          const unsigned* __restrict__ amaxb) {
    int idx = blockIdx.x * 256 + threadIdx.x;   // 131072 = 512 blocks
    int oc = idx >> 8, c = idx & 255;
    float inv = 127.0f / fmaxf(__uint_as_float(amaxb[1 + (oc >> 7)]), 1e-12f);
    const float* src = wsrc + (size_t)idx * 9;
    float v[9];
#pragma unroll
    for (int rs = 0; rs < 9; ++rs) v[rs] = src[rs];
#pragma unroll
    for (int rs = 0; rs < 9; ++rs) {
        float qf = fminf(fmaxf(rintf(v[rs] * inv), -128.f), 127.f);
        qw[((size_t)(rs * 512 + oc)) * 256 + c] = (signed char)(int)qf;
    }
}

// ---------------- conv : implicit GEMM with mfma_i32_16x16x64_i8 ----------------
// Round-6 structure (revert of round-5's failed global-A-gather, upsized from round-3):
// grid 2048 (XCD-swizzled: each XCD owns one image n), block 256 (4 waves).
// Block tile: 128 oc x 256 px (2 output rows). Wave = 128oc x 64px (8x4 fragments,
// acc 128 VGPR) -> 87 MFMA-ops per LDS byte (vs 64 in round 3); per-CU LDS traffic
// drops ~92us-worth -> ~84us-worth, co-critical with the 78us MFMA floor.
// LDS: xs[4 rows][130][64] staged per cb (33.3 KB) + wt[3 s][128 oc][64] staged per
// (cb, r) (24.6 KB) = 58 KB -> 2 blocks/CU preserved (that inter-block overlap is
// what round 4 proved essential). 12 phases, 96 MFMA/wave between barriers.
// Fragment LDS reads XOR-swizzled (proven round-3 pattern) via permuted GLOBAL q4.
__global__ __launch_bounds__(256, 2) void k_conv(
    const signed char* __restrict__ qx, const signed char* __restrict__ qw,
    const signed char* __restrict__ zb, const unsigned* __restrict__ amaxb,
    const float* __restrict__ bias, float* __restrict__ out) {
    __shared__ __align__(16) signed char xs[4 * 8320];      // 33280 B
    __shared__ __align__(16) signed char wt[3 * 128 * 64];  // 24576 B
    int orig = blockIdx.x;                      // 0..2047, nwg % 8 == 0
    int wgid = (orig & 7) * 256 + (orig >> 3);  // bijective XCD swizzle
    int rowpair = wgid >> 2, ocg = wgid & 3;    // ocg: 128-oc group == weight chunk
    int n = rowpair >> 6;                       // 64 rowpairs per image
    int h0 = (rowpair & 63) * 2;
    int t = threadIdx.x, wid = t >> 6, lane = t & 63;
    int p = lane & 15, hi = lane >> 4;
    int rowsel = wid >> 1, whalf = wid & 1;

    i32x4 acc[8][4] = {};

    auto stageX = [&](int cb) {
        // xs: 4 rows x 130 w x 4 q4 = 2080 x 16B, lane-linear LDS dest
#pragma unroll
        for (int i = 0; i < 9; ++i) {
            int idx = t + i * 256;
            if (idx < 2080) {
                int rowk = idx / 520;
                int j = idx - rowk * 520;
                int wr = j >> 2, q4 = j & 3;
                int wg = wr - 1;
                int hh = h0 - 1 + rowk;
                int q4s = q4 ^ ((wr >> 1) & 3);
                const signed char* src = (hh >= 0 && hh < 128 && wg >= 0 && wg < 128)
                    ? qx + (size_t)(n * 128 + hh) * 32768 + wg * 256 + cb * 64 + q4s * 16
                    : zb;
                llds16(src, xs + (size_t)(i * 256 + wid * 64) * 16);
            }
        }
    };
    auto stageW = [&](int cb, int r) {
        // wt: 3 s x 128 oc x 4 q4 = 1536 x 16B
#pragma unroll
        for (int i = 0; i < 6; ++i) {
            int idx = t + i * 256;       // 0..1535
            int s = idx >> 9, rem = idx & 511;
            int oc = rem >> 2, q4 = rem & 3;
            int q4s = q4 ^ ((oc >> 1) & 3);
            const signed char* src = qw
                + (size_t)((r * 3 + s) * 512 + ocg * 128 + oc) * 256 + cb * 64 + q4s * 16;
            llds16(src, wt + (size_t)(i * 256 + wid * 64) * 16);
        }
    };

    for (int cb = 0; cb < 4; ++cb) {
#pragma unroll
        for (int r = 0; r < 3; ++r) {
            if (r == 0) stageX(cb);
            stageW(cb, r);
            __syncthreads();               // staging landed (implicit vmcnt drain)
            int rowk = r + rowsel;
#pragma unroll
            for (int s = 0; s < 3; ++s) {
                i32x4 a[8], b[4];
#pragma unroll
                for (int mf = 0; mf < 8; ++mf) {
                    int ocr = mf * 16 + p;
                    a[mf] = *(const i32x4*)&wt[s * 8192 + ocr * 64
                                               + ((hi ^ ((ocr >> 1) & 3)) << 4)];
                }
#pragma unroll
                for (int nf = 0; nf < 4; ++nf) {
                    int wrow = whalf * 64 + nf * 16 + p + s;
                    b[nf] = *(const i32x4*)&xs[rowk * 8320 + wrow * 64
                                               + ((hi ^ ((wrow >> 1) & 3)) << 4)];
                }
#pragma unroll
                for (int mf = 0; mf < 8; ++mf)
#pragma unroll
                    for (int nf = 0; nf < 4; ++nf)
                        acc[mf][nf] = __builtin_amdgcn_mfma_i32_16x16x64_i8(
                            a[mf], b[nf], acc[mf][nf], 0, 0, 0);
            }
            __syncthreads();               // fragment reads done -> wt/xs reusable
        }
    }

    float sx = fmaxf(__uint_as_float(amaxb[0]), 1e-12f) / 127.0f;
    float sw = fmaxf(__uint_as_float(amaxb[1 + ocg]), 1e-12f) / 127.0f;
    float sc = sx * sw;
    int h = h0 + rowsel;
#pragma unroll
    for (int mf = 0; mf < 8; ++mf)
#pragma unroll
        for (int nf = 0; nf < 4; ++nf)
#pragma unroll
            for (int j = 0; j < 4; ++j) {
                int oc = ocg * 128 + mf * 16 + hi * 4 + j;
                int px = whalf * 64 + nf * 16 + p;
                out[((size_t)(n * 512 + oc) * 128 + h) * 128 + px] =
                    (float)acc[mf][nf][j] * sc + bias[oc];
            }
}

extern "C" void kernel_launch(void* const* d_in, const int* in_sizes, int n_in,
                              void* d_out, int out_size, void* d_ws, size_t ws_size,
                              hipStream_t stream) {
    const float* x    = (const float*)d_in[0];
    const float* wgt  = (const float*)d_in[1];
    const float* bias = (const float*)d_in[2];
    float* out = (float*)d_out;

    unsigned* amaxb = (unsigned*)d_ws;
    float* part = (float*)((char*)d_ws + 256);
    signed char* qx = (signed char*)d_ws + 16384;
    signed char* qw = (signed char*)d_ws + 16384 + 33554432;
    const signed char* zb = (const signed char*)d_ws + 64;   // 16B zeros for OOB redirect

    hipMemsetAsync(d_ws, 0, 256, stream);   // zb zeros (amax slots overwritten by k_amax2)

    k_amax<<<3200, 256, 0, stream>>>((const float4*)x, (const float4*)wgt, part);
    k_amax2<<<1, 256, 0, stream>>>(part, amaxb);
    k_quant_x<<<1024, 256, 0, stream>>>(x, qx, amaxb);
    k_quant_w<<<512, 256, 0, stream>>>(wgt, qw, amaxb);
    k_conv<<<dim3(2048), 256, 0, stream>>>(qx, qw, zb, amaxb, bias, out);
}